// Round 18
// baseline (165.652 us; speedup 1.0000x reference)
//
#include <hip/hip_runtime.h>
#include <hip/hip_bf16.h>
#include <math.h>

#define BB   8
#define NN   2048
#define CC   256
#define MTOT (BB * NN)   // 16384

typedef __bf16 bf16_t;
typedef bf16_t    bf16x8 __attribute__((ext_vector_type(8)));
typedef _Float16  halfx8 __attribute__((ext_vector_type(8)));
typedef float     floatx4 __attribute__((ext_vector_type(4)));

#define LOG2E 1.44269504088896f

// async global->LDS, 16 bytes per lane. LDS dest must be wave-uniform base + lane*16.
__device__ __forceinline__ void gl_lds16(const bf16_t* g, bf16_t* l) {
    __builtin_amdgcn_global_load_lds(
        (const __attribute__((address_space(1))) unsigned int*)g,
        (__attribute__((address_space(3))) unsigned int*)l, 16, 0, 0);
}

// ---------------------------------------------------------------------------
// qk projection, FUSED x-conversion: [q|k] = relu(x_fp32 @ WqkT^T + bqk).
// A (x) is fp32 in HBM and is REG-STAGED: load float4 x2 -> cvt bf16x8 in
// register -> ds_write_b128. LDS stays bf16 (16 KB); the ds_read/MFMA path is
// byte-identical to the proven bf16 kernel (R9's fp32-in-LDS regression
// avoided). B (WqkT) keeps gl_lds. Eliminates the cvt pass (~16 us + 100 MB).
// Grid dim3(128, 4): wgid = m + 128*n, 128 % 8 == 0 -> xcd = m % 8: the 4
// n-blocks sharing an x m-panel land on ONE XCD -> x re-reads are L2-hits
// (affinity proven -7 us in R16); stage-1 HBM traffic 134 -> ~67 MB.
// ---------------------------------------------------------------------------
__global__ __launch_bounds__(256, 3)
void gemm_qk(const float* __restrict__ X, const bf16_t* __restrict__ B,
             bf16_t* __restrict__ C, const float* __restrict__ bias)
{
    const int m0 = blockIdx.x * 128;
    const int n0 = blockIdx.y * 128;

    __shared__ bf16_t As[128 * 64];
    __shared__ bf16_t Bs[128 * 64];

    const int tid  = threadIdx.x;
    const int wid  = tid >> 6, lane = tid & 63;
    const int wm   = (wid >> 1) * 64, wn = (wid & 1) * 64;
    const int fr   = lane & 15;
    const int u16  = lane >> 4;           // 0..3
    const int fsw  = fr & 7;              // read-side XOR

    floatx4 acc[4][4] = {};

    for (int k0 = 0; k0 < 256; k0 += 64) {
        // B: gl_lds, source-side XOR (unchanged)
#pragma unroll
        for (int r = 0; r < 4; ++r) {
            const int lin = tid + r * 256;
            const int rw  = lin >> 3, kc = lin & 7;
            const int kcs = kc ^ (rw & 7);
            gl_lds16(B + (long)(n0 + rw) * 256 + k0 + kcs * 8, Bs + lin * 8);
        }
        // A: reg-staged fp32 -> bf16 -> ds_write (same source XOR, LDS linear)
#pragma unroll
        for (int r = 0; r < 4; ++r) {
            const int lin = tid + r * 256;
            const int rw  = lin >> 3, kc = lin & 7;
            const int kcs = kc ^ (rw & 7);
            const float* src = X + (long)(m0 + rw) * 256 + k0 + kcs * 8;
            const float4 lo = *(const float4*)(src);
            const float4 hi = *(const float4*)(src + 4);
            bf16x8 t;
            t[0] = (bf16_t)lo.x; t[1] = (bf16_t)lo.y;
            t[2] = (bf16_t)lo.z; t[3] = (bf16_t)lo.w;
            t[4] = (bf16_t)hi.x; t[5] = (bf16_t)hi.y;
            t[6] = (bf16_t)hi.z; t[7] = (bf16_t)hi.w;
            *(bf16x8*)(As + lin * 8) = t;
        }
        __syncthreads();
        bf16x8 af[4][2], bf[4][2];
#pragma unroll
        for (int f = 0; f < 4; ++f)
#pragma unroll
            for (int j = 0; j < 2; ++j) {
                const int chunk = (j * 4 + u16) ^ fsw;   // read-side XOR
                af[f][j] = *(const bf16x8*)(As + (wm + f * 16 + fr) * 64 + chunk * 8);
                bf[f][j] = *(const bf16x8*)(Bs + (wn + f * 16 + fr) * 64 + chunk * 8);
            }
#pragma unroll
        for (int j = 0; j < 2; ++j)
#pragma unroll
            for (int f = 0; f < 4; ++f)
#pragma unroll
                for (int g = 0; g < 4; ++g)
                    acc[f][g] = __builtin_amdgcn_mfma_f32_16x16x32_bf16(af[f][j], bf[g][j], acc[f][g], 0, 0, 0);
        __syncthreads();
    }

    // C/D layout: col = lane&15, row = (lane>>4)*4 + reg
    const int rbase = u16 * 4;
#pragma unroll
    for (int g = 0; g < 4; ++g) {
        const int n = n0 + wn + g * 16 + fr;
        const float bv = bias[n];
#pragma unroll
        for (int f = 0; f < 4; ++f) {
#pragma unroll
            for (int r = 0; r < 4; ++r) {
                const int m = m0 + wm + f * 16 + rbase + r;
                float v = acc[f][g][r] + bv;
                v = v > 0.0f ? v : 0.0f;
                C[(long)m * 512 + n] = (bf16_t)v;
            }
        }
    }
}

// ---------------------------------------------------------------------------
// FUSED second stage (both consume qk; no cross-dependency):
//   blocks [0, 2048):    St[m][n] = q[m]·k[n]  (fp16) + per-column stats
//                        (XCD-batch affinity, swz=16 decode)
//   blocks [2048, 2304): qmT[u][m] = sum_k WmT[u][k] * q[m][k]  (bf16)
// Same 128x128 BK=64 loop, byte-identical staging/MFMA.
// ---------------------------------------------------------------------------
__global__ __launch_bounds__(256, 3)
void gemm_fused(const bf16_t* __restrict__ qk, const bf16_t* __restrict__ WmT,
                _Float16* __restrict__ St, bf16_t* __restrict__ qmT,
                float* __restrict__ pm, float* __restrict__ pl)
{
    const int bid  = blockIdx.x;
    const bool isSt = bid < 2048;
    int b, m0, n0, myi;
    const bf16_t *A, *B;
    int lda;
    if (isSt) {
        b = bid & 7;
        const int r = bid >> 3;          // 0..255
        n0  = (r & 15) * 128;
        myi = r >> 4;                    // 0..15
        m0  = myi * 128;
        A   = qk + (long)b * NN * 512;         // q rows
        B   = qk + 256 + (long)b * NN * 512;   // k rows
        lda = 512;
    } else {
        const int q = bid - 2048;        // 0..255
        b = q & 7;
        const int r = q >> 3;            // 0..31
        n0  = (r & 15) * 128;
        m0  = (r >> 4) * 128;            // 0 or 128 (u dimension)
        myi = 0;
        A   = WmT;                       // u rows (no batch stride)
        B   = qk + (long)b * NN * 512;   // q rows (cols of qmT)
        lda = 256;
    }
    const int ldb = 512;

    __shared__ bf16_t As[128 * 64];
    __shared__ bf16_t Bs[128 * 64];
    __shared__ float  smx[4][4][16];
    __shared__ float  ssm[4][4][16];

    const int tid  = threadIdx.x;
    const int wid  = tid >> 6, lane = tid & 63;
    const int wm   = (wid >> 1) * 64, wn = (wid & 1) * 64;
    const int fr   = lane & 15;
    const int u16  = lane >> 4;           // 0..3
    const int fsw  = fr & 7;              // read-side XOR

    floatx4 acc[4][4] = {};

    for (int k0 = 0; k0 < 256; k0 += 64) {
#pragma unroll
        for (int r = 0; r < 4; ++r) {
            const int lin = tid + r * 256;
            const int rw  = lin >> 3, kc = lin & 7;
            const int kcs = kc ^ (rw & 7);        // source-side XOR (stage)
            gl_lds16(A + (long)(m0 + rw) * lda + k0 + kcs * 8, As + lin * 8);
            gl_lds16(B + (long)(n0 + rw) * ldb + k0 + kcs * 8, Bs + lin * 8);
        }
        __syncthreads();
        bf16x8 af[4][2], bf[4][2];
#pragma unroll
        for (int f = 0; f < 4; ++f)
#pragma unroll
            for (int j = 0; j < 2; ++j) {
                const int chunk = (j * 4 + u16) ^ fsw;   // read-side XOR
                af[f][j] = *(const bf16x8*)(As + (wm + f * 16 + fr) * 64 + chunk * 8);
                bf[f][j] = *(const bf16x8*)(Bs + (wn + f * 16 + fr) * 64 + chunk * 8);
            }
#pragma unroll
        for (int j = 0; j < 2; ++j)
#pragma unroll
            for (int f = 0; f < 4; ++f)
#pragma unroll
                for (int g = 0; g < 4; ++g)
                    acc[f][g] = __builtin_amdgcn_mfma_f32_16x16x32_bf16(af[f][j], bf[g][j], acc[f][g], 0, 0, 0);
        __syncthreads();
    }

    // C/D layout: col = lane&15, row = (lane>>4)*4 + reg
    const int rbase = u16 * 4;
    if (isSt) {
        _Float16* C = St + (long)b * NN * NN;
#pragma unroll
        for (int g = 0; g < 4; ++g) {
            const int n = n0 + wn + g * 16 + fr;
#pragma unroll
            for (int f = 0; f < 4; ++f)
#pragma unroll
                for (int r = 0; r < 4; ++r) {
                    const int m = m0 + wm + f * 16 + rbase + r;
                    C[(long)m * NN + n] = (_Float16)acc[f][g][r];
                }
        }
        // per-column (max, sumexp) partials over this block's 128 rows
        float lmax[4], lsum[4];
#pragma unroll
        for (int g = 0; g < 4; ++g) {
            float m = -1e30f;
#pragma unroll
            for (int f = 0; f < 4; ++f)
#pragma unroll
                for (int r = 0; r < 4; ++r) m = fmaxf(m, acc[f][g][r]);
            m = fmaxf(m, __shfl_xor(m, 16));
            m = fmaxf(m, __shfl_xor(m, 32));
            float s = 0.0f;
#pragma unroll
            for (int f = 0; f < 4; ++f)
#pragma unroll
                for (int r = 0; r < 4; ++r) s += __expf(acc[f][g][r] - m);
            s += __shfl_xor(s, 16);
            s += __shfl_xor(s, 32);
            lmax[g] = m; lsum[g] = s;
        }
        if (lane < 16) {
#pragma unroll
            for (int g = 0; g < 4; ++g) {
                smx[wid][g][lane] = lmax[g];
                ssm[wid][g][lane] = lsum[g];
            }
        }
        __syncthreads();
        if (tid < 128) {
            const int pair = tid >> 6;
            const int idx  = tid & 63;
            const int g = idx >> 4, f2 = idx & 15;
            const float m0v = smx[pair][g][f2], m1v = smx[pair + 2][g][f2];
            const float M = fmaxf(m0v, m1v);
            const float L = ssm[pair][g][f2] * __expf(m0v - M) +
                            ssm[pair + 2][g][f2] * __expf(m1v - M);
            const int n = n0 + pair * 64 + g * 16 + f2;
            const long o = ((long)b * 16 + myi) * NN + n;
            pm[o] = M;
            pl[o] = L;
        }
    } else {
        bf16_t* C = qmT + (long)b * 256 * NN;
#pragma unroll
        for (int g = 0; g < 4; ++g) {
            const int n = n0 + wn + g * 16 + fr;
#pragma unroll
            for (int f = 0; f < 4; ++f)
#pragma unroll
                for (int r = 0; r < 4; ++r) {
                    const int m = m0 + wm + f * 16 + rbase + r;
                    C[(long)m * NN + n] = (bf16_t)acc[f][g][r];
                }
        }
    }
}

// ---------------------------------------------------------------------------
// Merge 16 per-m-tile partials per column into c2[n] = (mx + ln L) * log2(e).
// ---------------------------------------------------------------------------
__global__ __launch_bounds__(256)
void stats_combine(const float* __restrict__ pm, const float* __restrict__ pl,
                   float* __restrict__ c2)
{
    const int i = blockIdx.x * 256 + threadIdx.x;
    const int b = i >> 11, n = i & 2047;
    float M = -1e30f, L = 0.0f;
#pragma unroll
    for (int t = 0; t < 16; ++t) {
        const long o = ((long)b * 16 + t) * NN + n;
        const float m = pm[o], l = pl[o];
        const float nm = fmaxf(M, m);
        L = L * __expf(M - nm) + l * __expf(m - nm);
        M = nm;
    }
    c2[i] = (M + logf(L)) * LOG2E;
}

// ---------------------------------------------------------------------------
// out[m][u] = relu( sum_n exp2(St[m][n]*log2e - c2[n]) * qmT[u][n] + bm[u] )
// v8 (FROZEN, best measured 48.8 us): round-0 v1 structure (32m x 128u,
// n-step 64, 4 blocks/CU) + XCD-batch affinity decode (FETCH 66->37 MB).
// ---------------------------------------------------------------------------
#define APAD 68
__global__ __launch_bounds__(256, 4)
void att_out(const _Float16* __restrict__ St, const bf16_t* __restrict__ qmT,
             const float* __restrict__ c2, const float* __restrict__ bm,
             float* __restrict__ out)
{
    const int bid = blockIdx.x;
    const int b   = bid & 7;            // batch -> XCD (wgid % 8)
    const int r   = bid >> 3;           // 0..127
    const int m0  = (r >> 1) * 32;      // m-block
    const int u0  = (r & 1) * 128;      // u-half
    const _Float16* S  = St  + (long)b * NN * NN;
    const bf16_t*   Q  = qmT + (long)b * 256 * NN;
    const float*    C2 = c2  + b * NN;
    float*          O  = out + (long)b * NN * 256;

    __shared__ bf16_t As[32 * APAD];  // 4.25 KB  P-tile (exp'd, bf16, padded)
    __shared__ bf16_t Bs[128 * 64];   // 16 KB    qmT tile (XOR-swizzled)

    const int tid  = threadIdx.x;
    const int wid  = tid >> 6, lane = tid & 63;
    const int wm2  = (wid >> 1) * 16;      // m-half per wave (0 or 16)
    const int wu   = (wid & 1) * 64;       // u-half per wave (0 or 64)
    const int fr   = lane & 15;
    const int u16  = lane >> 4;            // 0..3
    const int kb   = u16 * 8;
    const int fsw  = fr & 7;               // read-side XOR for Bs
    const int arow = tid >> 3;             // 0..31  (A staging row)
    const int aseg = tid & 7;              // 8 halves each

    const _Float16* Srow = S + (long)(m0 + arow) * NN + aseg * 8;

    floatx4 acc[4] = {};   // [g: u frags]

    for (int n0 = 0; n0 < NN; n0 += 64) {
        // B: qmT 128 rows x 64 cols bf16, 4 rounds of 256x16B, source-swizzled
#pragma unroll
        for (int r2 = 0; r2 < 4; ++r2) {
            const int lin = tid + r2 * 256;
            const int rw  = lin >> 3, kc = lin & 7;
            const int kcs = kc ^ (rw & 7);
            gl_lds16(Q + (long)(u0 + rw) * NN + n0 + kcs * 8, Bs + lin * 8);
        }
        // A: St 32x64 fp16, exp2(s*log2e - c2), pack bf16 -> padded LDS
        const halfx8 hv = *(const halfx8*)(Srow + n0);
        const float4 ca = *(const float4*)(C2 + n0 + aseg * 8);
        const float4 cb = *(const float4*)(C2 + n0 + aseg * 8 + 4);
        bf16x8 p;
        p[0] = (bf16_t)exp2f(fmaf((float)hv[0], LOG2E, -ca.x));
        p[1] = (bf16_t)exp2f(fmaf((float)hv[1], LOG2E, -ca.y));
        p[2] = (bf16_t)exp2f(fmaf((float)hv[2], LOG2E, -ca.z));
        p[3] = (bf16_t)exp2f(fmaf((float)hv[3], LOG2E, -ca.w));
        p[4] = (bf16_t)exp2f(fmaf((float)hv[4], LOG2E, -cb.x));
        p[5] = (bf16_t)exp2f(fmaf((float)hv[5], LOG2E, -cb.y));
        p[6] = (bf16_t)exp2f(fmaf((float)hv[6], LOG2E, -cb.z));
        p[7] = (bf16_t)exp2f(fmaf((float)hv[7], LOG2E, -cb.w));
        *(bf16x8*)(As + arow * APAD + aseg * 8) = p;
        __syncthreads();

        bf16x8 af[2], bg[4][2];
#pragma unroll
        for (int j = 0; j < 2; ++j)
            af[j] = *(const bf16x8*)(As + (wm2 + fr) * APAD + j * 32 + kb);
#pragma unroll
        for (int g = 0; g < 4; ++g)
#pragma unroll
            for (int j = 0; j < 2; ++j) {
                const int chunk = (j * 4 + u16) ^ fsw;
                bg[g][j] = *(const bf16x8*)(Bs + (wu + g * 16 + fr) * 64 + chunk * 8);
            }
#pragma unroll
        for (int j = 0; j < 2; ++j)
#pragma unroll
            for (int g = 0; g < 4; ++g)
                acc[g] = __builtin_amdgcn_mfma_f32_16x16x32_bf16(af[j], bg[g][j], acc[g], 0, 0, 0);
        __syncthreads();
    }

    // D layout: col(u) = lane&15, row(m) = (lane>>4)*4 + reg
    const int rbase = u16 * 4;
#pragma unroll
    for (int g = 0; g < 4; ++g) {
        const int u = u0 + wu + g * 16 + fr;
        const float bvv = bm[u];
#pragma unroll
        for (int r2 = 0; r2 < 4; ++r2) {
            const int m = m0 + wm2 + rbase + r2;
            const float v = acc[g][r2] + bvv;
            O[(long)m * 256 + u] = v > 0.0f ? v : 0.0f;
        }
    }
}

// ---------------------------------------------------------------------------
// Weight prep: z=0: Wq -> WqkT[0:256), z=1: Wk -> WqkT[256:512), z=2: Wm -> WmT.
// Block (0,0,0) also concatenates [bq|bk] into bqk.  (x cvt removed — fused
// into gemm_qk's reg-staged A path.)
// ---------------------------------------------------------------------------
__global__ __launch_bounds__(256)
void prep_w(const float* __restrict__ Wq, const float* __restrict__ Wk,
            const float* __restrict__ Wm, const float* __restrict__ bq,
            const float* __restrict__ bk, bf16_t* __restrict__ WqkT,
            bf16_t* __restrict__ WmT, float* __restrict__ bqk)
{
    const int z = blockIdx.z;
    const float* W = (z == 0) ? Wq : (z == 1) ? Wk : Wm;
    bf16_t* Wt = (z == 0) ? WqkT : (z == 1) ? (WqkT + 256 * 256) : WmT;
    __shared__ float t[32][33];
    const int n0 = blockIdx.x * 32, k0 = blockIdx.y * 32;
    const int tx = threadIdx.x & 31, ty = threadIdx.x >> 5;
    for (int i = ty; i < 32; i += 8) t[i][tx] = W[(k0 + i) * 256 + n0 + tx];
    __syncthreads();
    for (int i = ty; i < 32; i += 8) Wt[(n0 + i) * 256 + k0 + tx] = (bf16_t)t[tx][i];
    if (z == 0 && blockIdx.x == 0 && blockIdx.y == 0) {
        bqk[threadIdx.x]       = bq[threadIdx.x];
        bqk[256 + threadIdx.x] = bk[threadIdx.x];
    }
}

extern "C" void kernel_launch(void* const* d_in, const int* in_sizes, int n_in,
                              void* d_out, int out_size, void* d_ws, size_t ws_size,
                              hipStream_t stream)
{
    (void)in_sizes; (void)n_in; (void)out_size; (void)ws_size;
    const float* x  = (const float*)d_in[0];
    const float* Wq = (const float*)d_in[1];
    const float* bq = (const float*)d_in[2];
    const float* Wk = (const float*)d_in[3];
    const float* bk = (const float*)d_in[4];
    const float* Wm = (const float*)d_in[5];
    const float* bm = (const float*)d_in[6];
    float* out = (float*)d_out;

    // Workspace: St fp16 67.1 MB | qk 16.8 | qmT 8.4 | WqkT 0.26 | WmT 0.13 |
    // bqk | pm/pl 2x1 MB | c2 64 KB  (~94 MB).  x_bf eliminated.
    char* w = (char*)d_ws;
    _Float16* St   = (_Float16*)w;                  w += (size_t)BB * NN * NN * 2;
    bf16_t* qk     = (bf16_t*)w;                    w += (size_t)MTOT * 512 * 2;
    bf16_t* qmT    = (bf16_t*)w;                    w += (size_t)MTOT * 256 * 2;
    bf16_t* WqkT   = (bf16_t*)w;                    w += 512 * 256 * 2;
    bf16_t* WmT    = (bf16_t*)w;                    w += 256 * 256 * 2;
    float*  bqk    = (float*)w;                     w += 512 * 4;
    float*  pm     = (float*)w;                     w += (size_t)BB * 16 * NN * 4;
    float*  pl     = (float*)w;                     w += (size_t)BB * 16 * NN * 4;
    float*  c2b    = (float*)w;

    // stage 1: weight prep only (x cvt fused into gemm_qk)
    prep_w<<<dim3(8, 8, 3), 256, 0, stream>>>(Wq, Wk, Wm, bq, bk, WqkT, WmT, bqk);

    // [q | k] = relu(x @ [Wq|Wk] + [bq|bk])  — x fp32 reg-staged + converted
    // in the staging phase; grid (128,4): x m-panels XCD-local (R16: -7us).
    gemm_qk<<<dim3(128, 4, 1), 256, 0, stream>>>(x, WqkT, qk, bqk);

    // stage 3 (fused): St (fp16 + stats, blocks 0..2047, batch->XCD affinity)
    //                  ∥ qmT (bf16, blocks 2048..2303)
    gemm_fused<<<dim3(2304, 1, 1), 256, 0, stream>>>(
        qk, WmT, St, qmT, pm, pl);

    stats_combine<<<dim3(MTOT / 256), 256, 0, stream>>>(pm, pl, c2b);

    // out = relu(P~ @ qm + bm)  (v8 frozen, c2 from global)
    att_out<<<dim3(1024, 1, 1), 256, 0, stream>>>(St, qmT, c2b, bm, out);
}

// Round 19
// 162.284 us; speedup vs baseline: 1.0208x; 1.0208x over previous
//
#include <hip/hip_runtime.h>
#include <hip/hip_bf16.h>
#include <math.h>

#define BB   8
#define NN   2048
#define CC   256
#define MTOT (BB * NN)   // 16384

typedef __bf16 bf16_t;
typedef bf16_t    bf16x8 __attribute__((ext_vector_type(8)));
typedef _Float16  halfx8 __attribute__((ext_vector_type(8)));
typedef float     floatx4 __attribute__((ext_vector_type(4)));

#define LOG2E 1.44269504088896f

// async global->LDS, 16 bytes per lane. LDS dest must be wave-uniform base + lane*16.
__device__ __forceinline__ void gl_lds16(const bf16_t* g, bf16_t* l) {
    __builtin_amdgcn_global_load_lds(
        (const __attribute__((address_space(1))) unsigned int*)g,
        (__attribute__((address_space(3))) unsigned int*)l, 16, 0, 0);
}

// ---------------------------------------------------------------------------
// NT bf16 GEMM for the qk projection only: C[m][n] = relu(A[m]·B[n] + bias).
// 128x128 tile, K=256, BK=64, 256 threads. Grid dim3(128, 4):
//   m0 = blockIdx.x*128, n0 = blockIdx.y*128. Linear wgid = m + 128*n and
//   128 % 8 == 0  =>  xcd = m % 8: all 4 n-blocks sharing an x m-panel land
//   on ONE XCD -> x_bf re-reads are L2-hits (measured ~-7 us in R16).
// ---------------------------------------------------------------------------
template<int OMODE, bool BIASRELU>
__global__ __launch_bounds__(256, 3)
void gemm_nt(const bf16_t* __restrict__ A, const bf16_t* __restrict__ B,
             void* __restrict__ C, const float* __restrict__ bias,
             int lda, int ldb, int ldc,
             long strideA, long strideB, long strideC)
{
    const int b  = blockIdx.z;
    const int m0 = blockIdx.x * 128;
    const int n0 = blockIdx.y * 128;
    A += (long)b * strideA;
    B += (long)b * strideB;

    __shared__ bf16_t As[128 * 64];
    __shared__ bf16_t Bs[128 * 64];

    const int tid  = threadIdx.x;
    const int wid  = tid >> 6, lane = tid & 63;
    const int wm   = (wid >> 1) * 64, wn = (wid & 1) * 64;
    const int fr   = lane & 15;
    const int u16  = lane >> 4;           // 0..3
    const int fsw  = fr & 7;              // read-side XOR

    floatx4 acc[4][4] = {};

    for (int k0 = 0; k0 < 256; k0 += 64) {
#pragma unroll
        for (int r = 0; r < 4; ++r) {
            const int lin = tid + r * 256;
            const int rw  = lin >> 3, kc = lin & 7;
            const int kcs = kc ^ (rw & 7);        // source-side XOR (stage)
            gl_lds16(A + (long)(m0 + rw) * lda + k0 + kcs * 8, As + lin * 8);
            gl_lds16(B + (long)(n0 + rw) * ldb + k0 + kcs * 8, Bs + lin * 8);
        }
        __syncthreads();
        bf16x8 af[4][2], bf[4][2];
#pragma unroll
        for (int f = 0; f < 4; ++f)
#pragma unroll
            for (int j = 0; j < 2; ++j) {
                const int chunk = (j * 4 + u16) ^ fsw;   // read-side XOR
                af[f][j] = *(const bf16x8*)(As + (wm + f * 16 + fr) * 64 + chunk * 8);
                bf[f][j] = *(const bf16x8*)(Bs + (wn + f * 16 + fr) * 64 + chunk * 8);
            }
#pragma unroll
        for (int j = 0; j < 2; ++j)
#pragma unroll
            for (int f = 0; f < 4; ++f)
#pragma unroll
                for (int g = 0; g < 4; ++g)
                    acc[f][g] = __builtin_amdgcn_mfma_f32_16x16x32_bf16(af[f][j], bf[g][j], acc[f][g], 0, 0, 0);
        __syncthreads();
    }

    // C/D layout: col = lane&15, row = (lane>>4)*4 + reg
    const int rbase = u16 * 4;
#pragma unroll
    for (int g = 0; g < 4; ++g) {
        const int n = n0 + wn + g * 16 + fr;
        const float bv = BIASRELU ? bias[n] : 0.0f;
#pragma unroll
        for (int f = 0; f < 4; ++f) {
#pragma unroll
            for (int r = 0; r < 4; ++r) {
                const int m = m0 + wm + f * 16 + rbase + r;
                float v = acc[f][g][r] + bv;
                if (BIASRELU) v = v > 0.0f ? v : 0.0f;
                if (OMODE == 0)
                    ((float*)C)[(long)b * strideC + (long)m * ldc + n] = v;
                else if (OMODE == 1)
                    ((bf16_t*)C)[(long)b * strideC + (long)m * ldc + n] = (bf16_t)v;
                else
                    ((_Float16*)C)[(long)b * strideC + (long)m * ldc + n] = (_Float16)v;
            }
        }
    }
}

// ---------------------------------------------------------------------------
// FUSED second stage (both consume qk; no cross-dependency):
//   blocks [0, 2048):    St[m][n] = q[m]·k[n]  (fp16) + per-column stats
//                        (XCD-batch affinity, swz=16 decode)
//   blocks [2048, 2304): qmT[u][m] = sum_k WmT[u][k] * q[m][k]  (bf16)
// Same 128x128 BK=64 loop, byte-identical staging/MFMA.
// ---------------------------------------------------------------------------
__global__ __launch_bounds__(256, 3)
void gemm_fused(const bf16_t* __restrict__ qk, const bf16_t* __restrict__ WmT,
                _Float16* __restrict__ St, bf16_t* __restrict__ qmT,
                float* __restrict__ pm, float* __restrict__ pl)
{
    const int bid  = blockIdx.x;
    const bool isSt = bid < 2048;
    int b, m0, n0, myi;
    const bf16_t *A, *B;
    int lda;
    if (isSt) {
        b = bid & 7;
        const int r = bid >> 3;          // 0..255
        n0  = (r & 15) * 128;
        myi = r >> 4;                    // 0..15
        m0  = myi * 128;
        A   = qk + (long)b * NN * 512;         // q rows
        B   = qk + 256 + (long)b * NN * 512;   // k rows
        lda = 512;
    } else {
        const int q = bid - 2048;        // 0..255
        b = q & 7;
        const int r = q >> 3;            // 0..31
        n0  = (r & 15) * 128;
        m0  = (r >> 4) * 128;            // 0 or 128 (u dimension)
        myi = 0;
        A   = WmT;                       // u rows (no batch stride)
        B   = qk + (long)b * NN * 512;   // q rows (cols of qmT)
        lda = 256;
    }
    const int ldb = 512;

    __shared__ bf16_t As[128 * 64];
    __shared__ bf16_t Bs[128 * 64];
    __shared__ float  smx[4][4][16];
    __shared__ float  ssm[4][4][16];

    const int tid  = threadIdx.x;
    const int wid  = tid >> 6, lane = tid & 63;
    const int wm   = (wid >> 1) * 64, wn = (wid & 1) * 64;
    const int fr   = lane & 15;
    const int u16  = lane >> 4;           // 0..3
    const int fsw  = fr & 7;              // read-side XOR

    floatx4 acc[4][4] = {};

    for (int k0 = 0; k0 < 256; k0 += 64) {
#pragma unroll
        for (int r = 0; r < 4; ++r) {
            const int lin = tid + r * 256;
            const int rw  = lin >> 3, kc = lin & 7;
            const int kcs = kc ^ (rw & 7);        // source-side XOR (stage)
            gl_lds16(A + (long)(m0 + rw) * lda + k0 + kcs * 8, As + lin * 8);
            gl_lds16(B + (long)(n0 + rw) * ldb + k0 + kcs * 8, Bs + lin * 8);
        }
        __syncthreads();
        bf16x8 af[4][2], bf[4][2];
#pragma unroll
        for (int f = 0; f < 4; ++f)
#pragma unroll
            for (int j = 0; j < 2; ++j) {
                const int chunk = (j * 4 + u16) ^ fsw;   // read-side XOR
                af[f][j] = *(const bf16x8*)(As + (wm + f * 16 + fr) * 64 + chunk * 8);
                bf[f][j] = *(const bf16x8*)(Bs + (wn + f * 16 + fr) * 64 + chunk * 8);
            }
#pragma unroll
        for (int j = 0; j < 2; ++j)
#pragma unroll
            for (int f = 0; f < 4; ++f)
#pragma unroll
                for (int g = 0; g < 4; ++g)
                    acc[f][g] = __builtin_amdgcn_mfma_f32_16x16x32_bf16(af[f][j], bf[g][j], acc[f][g], 0, 0, 0);
        __syncthreads();
    }

    // C/D layout: col = lane&15, row = (lane>>4)*4 + reg
    const int rbase = u16 * 4;
    if (isSt) {
        _Float16* C = St + (long)b * NN * NN;
#pragma unroll
        for (int g = 0; g < 4; ++g) {
            const int n = n0 + wn + g * 16 + fr;
#pragma unroll
            for (int f = 0; f < 4; ++f)
#pragma unroll
                for (int r = 0; r < 4; ++r) {
                    const int m = m0 + wm + f * 16 + rbase + r;
                    C[(long)m * NN + n] = (_Float16)acc[f][g][r];
                }
        }
        // per-column (max, sumexp) partials over this block's 128 rows
        float lmax[4], lsum[4];
#pragma unroll
        for (int g = 0; g < 4; ++g) {
            float m = -1e30f;
#pragma unroll
            for (int f = 0; f < 4; ++f)
#pragma unroll
                for (int r = 0; r < 4; ++r) m = fmaxf(m, acc[f][g][r]);
            m = fmaxf(m, __shfl_xor(m, 16));
            m = fmaxf(m, __shfl_xor(m, 32));
            float s = 0.0f;
#pragma unroll
            for (int f = 0; f < 4; ++f)
#pragma unroll
                for (int r = 0; r < 4; ++r) s += __expf(acc[f][g][r] - m);
            s += __shfl_xor(s, 16);
            s += __shfl_xor(s, 32);
            lmax[g] = m; lsum[g] = s;
        }
        if (lane < 16) {
#pragma unroll
            for (int g = 0; g < 4; ++g) {
                smx[wid][g][lane] = lmax[g];
                ssm[wid][g][lane] = lsum[g];
            }
        }
        __syncthreads();
        if (tid < 128) {
            const int pair = tid >> 6;
            const int idx  = tid & 63;
            const int g = idx >> 4, f2 = idx & 15;
            const float m0v = smx[pair][g][f2], m1v = smx[pair + 2][g][f2];
            const float M = fmaxf(m0v, m1v);
            const float L = ssm[pair][g][f2] * __expf(m0v - M) +
                            ssm[pair + 2][g][f2] * __expf(m1v - M);
            const int n = n0 + pair * 64 + g * 16 + f2;
            const long o = ((long)b * 16 + myi) * NN + n;
            pm[o] = M;
            pl[o] = L;
        }
    } else {
        bf16_t* C = qmT + (long)b * 256 * NN;
#pragma unroll
        for (int g = 0; g < 4; ++g) {
            const int n = n0 + wn + g * 16 + fr;
#pragma unroll
            for (int f = 0; f < 4; ++f)
#pragma unroll
                for (int r = 0; r < 4; ++r) {
                    const int m = m0 + wm + f * 16 + rbase + r;
                    C[(long)m * NN + n] = (bf16_t)acc[f][g][r];
                }
        }
    }
}

// ---------------------------------------------------------------------------
// Merge 16 per-m-tile partials per column into c2[n] = (mx + ln L) * log2(e).
// ---------------------------------------------------------------------------
__global__ __launch_bounds__(256)
void stats_combine(const float* __restrict__ pm, const float* __restrict__ pl,
                   float* __restrict__ c2)
{
    const int i = blockIdx.x * 256 + threadIdx.x;
    const int b = i >> 11, n = i & 2047;
    float M = -1e30f, L = 0.0f;
#pragma unroll
    for (int t = 0; t < 16; ++t) {
        const long o = ((long)b * 16 + t) * NN + n;
        const float m = pm[o], l = pl[o];
        const float nm = fmaxf(M, m);
        L = L * __expf(M - nm) + l * __expf(m - nm);
        M = nm;
    }
    c2[i] = (M + logf(L)) * LOG2E;
}

// ---------------------------------------------------------------------------
// out[m][u] = relu( sum_n exp2(St[m][n]*log2e - c2[n]) * qmT[u][n] + bm[u] )
// v8 (FROZEN, best measured 48.8 us): round-0 v1 structure (32m x 128u,
// n-step 64, 4 blocks/CU) + XCD-batch affinity decode (FETCH 66->37 MB).
// ---------------------------------------------------------------------------
#define APAD 68
__global__ __launch_bounds__(256, 4)
void att_out(const _Float16* __restrict__ St, const bf16_t* __restrict__ qmT,
             const float* __restrict__ c2, const float* __restrict__ bm,
             float* __restrict__ out)
{
    const int bid = blockIdx.x;
    const int b   = bid & 7;            // batch -> XCD (wgid % 8)
    const int r   = bid >> 3;           // 0..127
    const int m0  = (r >> 1) * 32;      // m-block
    const int u0  = (r & 1) * 128;      // u-half
    const _Float16* S  = St  + (long)b * NN * NN;
    const bf16_t*   Q  = qmT + (long)b * 256 * NN;
    const float*    C2 = c2  + b * NN;
    float*          O  = out + (long)b * NN * 256;

    __shared__ bf16_t As[32 * APAD];  // 4.25 KB  P-tile (exp'd, bf16, padded)
    __shared__ bf16_t Bs[128 * 64];   // 16 KB    qmT tile (XOR-swizzled)

    const int tid  = threadIdx.x;
    const int wid  = tid >> 6, lane = tid & 63;
    const int wm2  = (wid >> 1) * 16;      // m-half per wave (0 or 16)
    const int wu   = (wid & 1) * 64;       // u-half per wave (0 or 64)
    const int fr   = lane & 15;
    const int u16  = lane >> 4;            // 0..3
    const int kb   = u16 * 8;
    const int fsw  = fr & 7;               // read-side XOR for Bs
    const int arow = tid >> 3;             // 0..31  (A staging row)
    const int aseg = tid & 7;              // 8 halves each

    const _Float16* Srow = S + (long)(m0 + arow) * NN + aseg * 8;

    floatx4 acc[4] = {};   // [g: u frags]

    for (int n0 = 0; n0 < NN; n0 += 64) {
        // B: qmT 128 rows x 64 cols bf16, 4 rounds of 256x16B, source-swizzled
#pragma unroll
        for (int r2 = 0; r2 < 4; ++r2) {
            const int lin = tid + r2 * 256;
            const int rw  = lin >> 3, kc = lin & 7;
            const int kcs = kc ^ (rw & 7);
            gl_lds16(Q + (long)(u0 + rw) * NN + n0 + kcs * 8, Bs + lin * 8);
        }
        // A: St 32x64 fp16, exp2(s*log2e - c2), pack bf16 -> padded LDS
        const halfx8 hv = *(const halfx8*)(Srow + n0);
        const float4 ca = *(const float4*)(C2 + n0 + aseg * 8);
        const float4 cb = *(const float4*)(C2 + n0 + aseg * 8 + 4);
        bf16x8 p;
        p[0] = (bf16_t)exp2f(fmaf((float)hv[0], LOG2E, -ca.x));
        p[1] = (bf16_t)exp2f(fmaf((float)hv[1], LOG2E, -ca.y));
        p[2] = (bf16_t)exp2f(fmaf((float)hv[2], LOG2E, -ca.z));
        p[3] = (bf16_t)exp2f(fmaf((float)hv[3], LOG2E, -ca.w));
        p[4] = (bf16_t)exp2f(fmaf((float)hv[4], LOG2E, -cb.x));
        p[5] = (bf16_t)exp2f(fmaf((float)hv[5], LOG2E, -cb.y));
        p[6] = (bf16_t)exp2f(fmaf((float)hv[6], LOG2E, -cb.z));
        p[7] = (bf16_t)exp2f(fmaf((float)hv[7], LOG2E, -cb.w));
        *(bf16x8*)(As + arow * APAD + aseg * 8) = p;
        __syncthreads();

        bf16x8 af[2], bg[4][2];
#pragma unroll
        for (int j = 0; j < 2; ++j)
            af[j] = *(const bf16x8*)(As + (wm2 + fr) * APAD + j * 32 + kb);
#pragma unroll
        for (int g = 0; g < 4; ++g)
#pragma unroll
            for (int j = 0; j < 2; ++j) {
                const int chunk = (j * 4 + u16) ^ fsw;
                bg[g][j] = *(const bf16x8*)(Bs + (wu + g * 16 + fr) * 64 + chunk * 8);
            }
#pragma unroll
        for (int j = 0; j < 2; ++j)
#pragma unroll
            for (int g = 0; g < 4; ++g)
                acc[g] = __builtin_amdgcn_mfma_f32_16x16x32_bf16(af[j], bg[g][j], acc[g], 0, 0, 0);
        __syncthreads();
    }

    // D layout: col(u) = lane&15, row(m) = (lane>>4)*4 + reg
    const int rbase = u16 * 4;
#pragma unroll
    for (int g = 0; g < 4; ++g) {
        const int u = u0 + wu + g * 16 + fr;
        const float bvv = bm[u];
#pragma unroll
        for (int r2 = 0; r2 < 4; ++r2) {
            const int m = m0 + wm2 + rbase + r2;
            const float v = acc[g][r2] + bvv;
            O[(long)m * 256 + u] = v > 0.0f ? v : 0.0f;
        }
    }
}

// ---------------------------------------------------------------------------
// FUSED first stage: blocks [0,2048) = x fp32->bf16 cvt; [2048,2240) = weight
// transpose prep. Independent work; block-uniform branch.
// ---------------------------------------------------------------------------
__global__ __launch_bounds__(256)
void cvt_prep(const float* __restrict__ x, bf16_t* __restrict__ x_bf,
              const float* __restrict__ Wq, const float* __restrict__ Wk,
              const float* __restrict__ Wm, const float* __restrict__ bq,
              const float* __restrict__ bk, bf16_t* __restrict__ WqkT,
              bf16_t* __restrict__ WmT, float* __restrict__ bqk)
{
    __shared__ float t[32][33];
    const int bid = blockIdx.x;
    if (bid < 2048) {
        const long i = ((long)bid * 256 + threadIdx.x) * 8;
        const float4 a = *(const float4*)(x + i);
        const float4 b = *(const float4*)(x + i + 4);
        bf16x8 o;
        o[0] = (bf16_t)a.x; o[1] = (bf16_t)a.y; o[2] = (bf16_t)a.z; o[3] = (bf16_t)a.w;
        o[4] = (bf16_t)b.x; o[5] = (bf16_t)b.y; o[6] = (bf16_t)b.z; o[7] = (bf16_t)b.w;
        *(bf16x8*)(x_bf + i) = o;
    } else {
        const int q = bid - 2048;        // 0..191
        const int z = q >> 6;            // 0..2
        const int xy = q & 63;
        const int n0 = (xy & 7) * 32, k0 = (xy >> 3) * 32;
        const float* W = (z == 0) ? Wq : (z == 1) ? Wk : Wm;
        bf16_t* Wt = (z == 0) ? WqkT : (z == 1) ? (WqkT + 256 * 256) : WmT;
        const int tx = threadIdx.x & 31, ty = threadIdx.x >> 5;
        for (int i2 = ty; i2 < 32; i2 += 8) t[i2][tx] = W[(k0 + i2) * 256 + n0 + tx];
        __syncthreads();
        for (int i2 = ty; i2 < 32; i2 += 8) Wt[(n0 + i2) * 256 + k0 + tx] = (bf16_t)t[tx][i2];
        if (q == 0) {
            bqk[threadIdx.x]       = bq[threadIdx.x];
            bqk[256 + threadIdx.x] = bk[threadIdx.x];
        }
    }
}

extern "C" void kernel_launch(void* const* d_in, const int* in_sizes, int n_in,
                              void* d_out, int out_size, void* d_ws, size_t ws_size,
                              hipStream_t stream)
{
    (void)in_sizes; (void)n_in; (void)out_size; (void)ws_size;
    const float* x  = (const float*)d_in[0];
    const float* Wq = (const float*)d_in[1];
    const float* bq = (const float*)d_in[2];
    const float* Wk = (const float*)d_in[3];
    const float* bk = (const float*)d_in[4];
    const float* Wm = (const float*)d_in[5];
    const float* bm = (const float*)d_in[6];
    float* out = (float*)d_out;

    // Workspace: St fp16 67.1 MB | x_bf 8.4 | qk 16.8 | qmT 8.4 |
    // WqkT 0.26 | WmT 0.13 | bqk | pm/pl 2x1 MB | c2 64 KB  (~103 MB)
    char* w = (char*)d_ws;
    _Float16* St   = (_Float16*)w;                  w += (size_t)BB * NN * NN * 2;
    bf16_t* x_bf   = (bf16_t*)w;                    w += (size_t)MTOT * 256 * 2;
    bf16_t* qk     = (bf16_t*)w;                    w += (size_t)MTOT * 512 * 2;
    bf16_t* qmT    = (bf16_t*)w;                    w += (size_t)MTOT * 256 * 2;
    bf16_t* WqkT   = (bf16_t*)w;                    w += 512 * 256 * 2;
    bf16_t* WmT    = (bf16_t*)w;                    w += 256 * 256 * 2;
    float*  bqk    = (float*)w;                     w += 512 * 4;
    float*  pm     = (float*)w;                     w += (size_t)BB * 16 * NN * 4;
    float*  pl     = (float*)w;                     w += (size_t)BB * 16 * NN * 4;
    float*  c2b    = (float*)w;

    // stage 1: cvt + weight prep (fused, 2240 blocks)
    cvt_prep<<<dim3(2240, 1, 1), 256, 0, stream>>>(
        x, x_bf, Wq, Wk, Wm, bq, bk, WqkT, WmT, bqk);

    // [q | k] = relu(x @ [Wq|Wk] + [bq|bk])  (bf16, ldc=512)
    // Grid (128,4): wgid = m + 128*n -> xcd = m%8, x panels L2-local (R16: -7us).
    gemm_nt<1, true><<<dim3(128, 4, 1), 256, 0, stream>>>(
        x_bf, WqkT, qk, bqk, 256, 256, 512, 0, 0, 0);

    // stage 3 (fused): St (fp16 + stats, blocks 0..2047, batch->XCD affinity)
    //                  ∥ qmT (bf16, blocks 2048..2303)
    gemm_fused<<<dim3(2304, 1, 1), 256, 0, stream>>>(
        qk, WmT, St, qmT, pm, pl);

    stats_combine<<<dim3(MTOT / 256), 256, 0, stream>>>(pm, pl, c2b);

    // out = relu(P~ @ qm + bm)  (v8 frozen, c2 from global)
    att_out<<<dim3(1024, 1, 1), 256, 0, stream>>>(St, qmT, c2b, bm, out);
}

// Round 20
// 162.049 us; speedup vs baseline: 1.0222x; 1.0014x over previous
//
#include <hip/hip_runtime.h>
#include <hip/hip_bf16.h>
#include <math.h>

#define BB   8
#define NN   2048
#define CC   256
#define MTOT (BB * NN)   // 16384

typedef __bf16 bf16_t;
typedef bf16_t    bf16x8 __attribute__((ext_vector_type(8)));
typedef _Float16  halfx8 __attribute__((ext_vector_type(8)));
typedef float     floatx4 __attribute__((ext_vector_type(4)));

#define LOG2E 1.44269504088896f

// async global->LDS, 16 bytes per lane. LDS dest must be wave-uniform base + lane*16.
__device__ __forceinline__ void gl_lds16(const bf16_t* g, bf16_t* l) {
    __builtin_amdgcn_global_load_lds(
        (const __attribute__((address_space(1))) unsigned int*)g,
        (__attribute__((address_space(3))) unsigned int*)l, 16, 0, 0);
}

// ---------------------------------------------------------------------------
// NT bf16 GEMM for the qk projection only: C[m][n] = relu(A[m]·B[n] + bias).
// 128x128 tile, K=256, BK=64, 256 threads. Grid dim3(128, 4):
//   m0 = blockIdx.x*128, n0 = blockIdx.y*128. Linear wgid = m + 128*n and
//   128 % 8 == 0  =>  xcd = m % 8: all 4 n-blocks sharing an x m-panel land
//   on ONE XCD -> x_bf re-reads are L2-hits (measured ~-7 us in R16).
// ---------------------------------------------------------------------------
template<int OMODE, bool BIASRELU>
__global__ __launch_bounds__(256, 3)
void gemm_nt(const bf16_t* __restrict__ A, const bf16_t* __restrict__ B,
             void* __restrict__ C, const float* __restrict__ bias,
             int lda, int ldb, int ldc,
             long strideA, long strideB, long strideC)
{
    const int b  = blockIdx.z;
    const int m0 = blockIdx.x * 128;
    const int n0 = blockIdx.y * 128;
    A += (long)b * strideA;
    B += (long)b * strideB;

    __shared__ bf16_t As[128 * 64];
    __shared__ bf16_t Bs[128 * 64];

    const int tid  = threadIdx.x;
    const int wid  = tid >> 6, lane = tid & 63;
    const int wm   = (wid >> 1) * 64, wn = (wid & 1) * 64;
    const int fr   = lane & 15;
    const int u16  = lane >> 4;           // 0..3
    const int fsw  = fr & 7;              // read-side XOR

    floatx4 acc[4][4] = {};

    for (int k0 = 0; k0 < 256; k0 += 64) {
#pragma unroll
        for (int r = 0; r < 4; ++r) {
            const int lin = tid + r * 256;
            const int rw  = lin >> 3, kc = lin & 7;
            const int kcs = kc ^ (rw & 7);        // source-side XOR (stage)
            gl_lds16(A + (long)(m0 + rw) * lda + k0 + kcs * 8, As + lin * 8);
            gl_lds16(B + (long)(n0 + rw) * ldb + k0 + kcs * 8, Bs + lin * 8);
        }
        __syncthreads();
        bf16x8 af[4][2], bf[4][2];
#pragma unroll
        for (int f = 0; f < 4; ++f)
#pragma unroll
            for (int j = 0; j < 2; ++j) {
                const int chunk = (j * 4 + u16) ^ fsw;   // read-side XOR
                af[f][j] = *(const bf16x8*)(As + (wm + f * 16 + fr) * 64 + chunk * 8);
                bf[f][j] = *(const bf16x8*)(Bs + (wn + f * 16 + fr) * 64 + chunk * 8);
            }
#pragma unroll
        for (int j = 0; j < 2; ++j)
#pragma unroll
            for (int f = 0; f < 4; ++f)
#pragma unroll
                for (int g = 0; g < 4; ++g)
                    acc[f][g] = __builtin_amdgcn_mfma_f32_16x16x32_bf16(af[f][j], bf[g][j], acc[f][g], 0, 0, 0);
        __syncthreads();
    }

    // C/D layout: col = lane&15, row = (lane>>4)*4 + reg
    const int rbase = u16 * 4;
#pragma unroll
    for (int g = 0; g < 4; ++g) {
        const int n = n0 + wn + g * 16 + fr;
        const float bv = BIASRELU ? bias[n] : 0.0f;
#pragma unroll
        for (int f = 0; f < 4; ++f) {
#pragma unroll
            for (int r = 0; r < 4; ++r) {
                const int m = m0 + wm + f * 16 + rbase + r;
                float v = acc[f][g][r] + bv;
                if (BIASRELU) v = v > 0.0f ? v : 0.0f;
                if (OMODE == 0)
                    ((float*)C)[(long)b * strideC + (long)m * ldc + n] = v;
                else if (OMODE == 1)
                    ((bf16_t*)C)[(long)b * strideC + (long)m * ldc + n] = (bf16_t)v;
                else
                    ((_Float16*)C)[(long)b * strideC + (long)m * ldc + n] = (_Float16)v;
            }
        }
    }
}

// ---------------------------------------------------------------------------
// FUSED second stage (both consume qk; no cross-dependency):
//   blocks [0, 2048):    St[m][n] = q[m]·k[n]  (fp16) + per-column stats
//                        (XCD-batch affinity, swz=16 decode)
//   blocks [2048, 2304): qmT[u][m] = sum_k WmT[u][k] * q[m][k]  (bf16)
// Same 128x128 BK=64 loop, byte-identical staging/MFMA.
// ---------------------------------------------------------------------------
__global__ __launch_bounds__(256, 3)
void gemm_fused(const bf16_t* __restrict__ qk, const bf16_t* __restrict__ WmT,
                _Float16* __restrict__ St, bf16_t* __restrict__ qmT,
                float* __restrict__ pm, float* __restrict__ pl)
{
    const int bid  = blockIdx.x;
    const bool isSt = bid < 2048;
    int b, m0, n0, myi;
    const bf16_t *A, *B;
    int lda;
    if (isSt) {
        b = bid & 7;
        const int r = bid >> 3;          // 0..255
        n0  = (r & 15) * 128;
        myi = r >> 4;                    // 0..15
        m0  = myi * 128;
        A   = qk + (long)b * NN * 512;         // q rows
        B   = qk + 256 + (long)b * NN * 512;   // k rows
        lda = 512;
    } else {
        const int q = bid - 2048;        // 0..255
        b = q & 7;
        const int r = q >> 3;            // 0..31
        n0  = (r & 15) * 128;
        m0  = (r >> 4) * 128;            // 0 or 128 (u dimension)
        myi = 0;
        A   = WmT;                       // u rows (no batch stride)
        B   = qk + (long)b * NN * 512;   // q rows (cols of qmT)
        lda = 256;
    }
    const int ldb = 512;

    __shared__ bf16_t As[128 * 64];
    __shared__ bf16_t Bs[128 * 64];
    __shared__ float  smx[4][4][16];
    __shared__ float  ssm[4][4][16];

    const int tid  = threadIdx.x;
    const int wid  = tid >> 6, lane = tid & 63;
    const int wm   = (wid >> 1) * 64, wn = (wid & 1) * 64;
    const int fr   = lane & 15;
    const int u16  = lane >> 4;           // 0..3
    const int fsw  = fr & 7;              // read-side XOR

    floatx4 acc[4][4] = {};

    for (int k0 = 0; k0 < 256; k0 += 64) {
#pragma unroll
        for (int r = 0; r < 4; ++r) {
            const int lin = tid + r * 256;
            const int rw  = lin >> 3, kc = lin & 7;
            const int kcs = kc ^ (rw & 7);        // source-side XOR (stage)
            gl_lds16(A + (long)(m0 + rw) * lda + k0 + kcs * 8, As + lin * 8);
            gl_lds16(B + (long)(n0 + rw) * ldb + k0 + kcs * 8, Bs + lin * 8);
        }
        __syncthreads();
        bf16x8 af[4][2], bf[4][2];
#pragma unroll
        for (int f = 0; f < 4; ++f)
#pragma unroll
            for (int j = 0; j < 2; ++j) {
                const int chunk = (j * 4 + u16) ^ fsw;   // read-side XOR
                af[f][j] = *(const bf16x8*)(As + (wm + f * 16 + fr) * 64 + chunk * 8);
                bf[f][j] = *(const bf16x8*)(Bs + (wn + f * 16 + fr) * 64 + chunk * 8);
            }
#pragma unroll
        for (int j = 0; j < 2; ++j)
#pragma unroll
            for (int f = 0; f < 4; ++f)
#pragma unroll
                for (int g = 0; g < 4; ++g)
                    acc[f][g] = __builtin_amdgcn_mfma_f32_16x16x32_bf16(af[f][j], bf[g][j], acc[f][g], 0, 0, 0);
        __syncthreads();
    }

    // C/D layout: col = lane&15, row = (lane>>4)*4 + reg
    const int rbase = u16 * 4;
    if (isSt) {
        _Float16* C = St + (long)b * NN * NN;
#pragma unroll
        for (int g = 0; g < 4; ++g) {
            const int n = n0 + wn + g * 16 + fr;
#pragma unroll
            for (int f = 0; f < 4; ++f)
#pragma unroll
                for (int r = 0; r < 4; ++r) {
                    const int m = m0 + wm + f * 16 + rbase + r;
                    C[(long)m * NN + n] = (_Float16)acc[f][g][r];
                }
        }
        // per-column (max, sumexp) partials over this block's 128 rows
        float lmax[4], lsum[4];
#pragma unroll
        for (int g = 0; g < 4; ++g) {
            float m = -1e30f;
#pragma unroll
            for (int f = 0; f < 4; ++f)
#pragma unroll
                for (int r = 0; r < 4; ++r) m = fmaxf(m, acc[f][g][r]);
            m = fmaxf(m, __shfl_xor(m, 16));
            m = fmaxf(m, __shfl_xor(m, 32));
            float s = 0.0f;
#pragma unroll
            for (int f = 0; f < 4; ++f)
#pragma unroll
                for (int r = 0; r < 4; ++r) s += __expf(acc[f][g][r] - m);
            s += __shfl_xor(s, 16);
            s += __shfl_xor(s, 32);
            lmax[g] = m; lsum[g] = s;
        }
        if (lane < 16) {
#pragma unroll
            for (int g = 0; g < 4; ++g) {
                smx[wid][g][lane] = lmax[g];
                ssm[wid][g][lane] = lsum[g];
            }
        }
        __syncthreads();
        if (tid < 128) {
            const int pair = tid >> 6;
            const int idx  = tid & 63;
            const int g = idx >> 4, f2 = idx & 15;
            const float m0v = smx[pair][g][f2], m1v = smx[pair + 2][g][f2];
            const float M = fmaxf(m0v, m1v);
            const float L = ssm[pair][g][f2] * __expf(m0v - M) +
                            ssm[pair + 2][g][f2] * __expf(m1v - M);
            const int n = n0 + pair * 64 + g * 16 + f2;
            const long o = ((long)b * 16 + myi) * NN + n;
            pm[o] = M;
            pl[o] = L;
        }
    } else {
        bf16_t* C = qmT + (long)b * 256 * NN;
#pragma unroll
        for (int g = 0; g < 4; ++g) {
            const int n = n0 + wn + g * 16 + fr;
#pragma unroll
            for (int f = 0; f < 4; ++f)
#pragma unroll
                for (int r = 0; r < 4; ++r) {
                    const int m = m0 + wm + f * 16 + rbase + r;
                    C[(long)m * NN + n] = (bf16_t)acc[f][g][r];
                }
        }
    }
}

// ---------------------------------------------------------------------------
// Merge 16 per-m-tile partials per column into c2[n] = (mx + ln L) * log2(e).
// ---------------------------------------------------------------------------
__global__ __launch_bounds__(256)
void stats_combine(const float* __restrict__ pm, const float* __restrict__ pl,
                   float* __restrict__ c2)
{
    const int i = blockIdx.x * 256 + threadIdx.x;
    const int b = i >> 11, n = i & 2047;
    float M = -1e30f, L = 0.0f;
#pragma unroll
    for (int t = 0; t < 16; ++t) {
        const long o = ((long)b * 16 + t) * NN + n;
        const float m = pm[o], l = pl[o];
        const float nm = fmaxf(M, m);
        L = L * __expf(M - nm) + l * __expf(m - nm);
        M = nm;
    }
    c2[i] = (M + logf(L)) * LOG2E;
}

// ---------------------------------------------------------------------------
// out[m][u] = relu( sum_n exp2(St[m][n]*log2e - c2[n]) * qmT[u][n] + bm[u] )
// v8 (FROZEN, best measured 48.8 us): round-0 v1 structure (32m x 128u,
// n-step 64, 4 blocks/CU) + XCD-batch affinity decode (FETCH 66->37 MB).
// ---------------------------------------------------------------------------
#define APAD 68
__global__ __launch_bounds__(256, 4)
void att_out(const _Float16* __restrict__ St, const bf16_t* __restrict__ qmT,
             const float* __restrict__ c2, const float* __restrict__ bm,
             float* __restrict__ out)
{
    const int bid = blockIdx.x;
    const int b   = bid & 7;            // batch -> XCD (wgid % 8)
    const int r   = bid >> 3;           // 0..127
    const int m0  = (r >> 1) * 32;      // m-block
    const int u0  = (r & 1) * 128;      // u-half
    const _Float16* S  = St  + (long)b * NN * NN;
    const bf16_t*   Q  = qmT + (long)b * 256 * NN;
    const float*    C2 = c2  + b * NN;
    float*          O  = out + (long)b * NN * 256;

    __shared__ bf16_t As[32 * APAD];  // 4.25 KB  P-tile (exp'd, bf16, padded)
    __shared__ bf16_t Bs[128 * 64];   // 16 KB    qmT tile (XOR-swizzled)

    const int tid  = threadIdx.x;
    const int wid  = tid >> 6, lane = tid & 63;
    const int wm2  = (wid >> 1) * 16;      // m-half per wave (0 or 16)
    const int wu   = (wid & 1) * 64;       // u-half per wave (0 or 64)
    const int fr   = lane & 15;
    const int u16  = lane >> 4;            // 0..3
    const int kb   = u16 * 8;
    const int fsw  = fr & 7;               // read-side XOR for Bs
    const int arow = tid >> 3;             // 0..31  (A staging row)
    const int aseg = tid & 7;              // 8 halves each

    const _Float16* Srow = S + (long)(m0 + arow) * NN + aseg * 8;

    floatx4 acc[4] = {};   // [g: u frags]

    for (int n0 = 0; n0 < NN; n0 += 64) {
        // B: qmT 128 rows x 64 cols bf16, 4 rounds of 256x16B, source-swizzled
#pragma unroll
        for (int r2 = 0; r2 < 4; ++r2) {
            const int lin = tid + r2 * 256;
            const int rw  = lin >> 3, kc = lin & 7;
            const int kcs = kc ^ (rw & 7);
            gl_lds16(Q + (long)(u0 + rw) * NN + n0 + kcs * 8, Bs + lin * 8);
        }
        // A: St 32x64 fp16, exp2(s*log2e - c2), pack bf16 -> padded LDS
        const halfx8 hv = *(const halfx8*)(Srow + n0);
        const float4 ca = *(const float4*)(C2 + n0 + aseg * 8);
        const float4 cb = *(const float4*)(C2 + n0 + aseg * 8 + 4);
        bf16x8 p;
        p[0] = (bf16_t)exp2f(fmaf((float)hv[0], LOG2E, -ca.x));
        p[1] = (bf16_t)exp2f(fmaf((float)hv[1], LOG2E, -ca.y));
        p[2] = (bf16_t)exp2f(fmaf((float)hv[2], LOG2E, -ca.z));
        p[3] = (bf16_t)exp2f(fmaf((float)hv[3], LOG2E, -ca.w));
        p[4] = (bf16_t)exp2f(fmaf((float)hv[4], LOG2E, -cb.x));
        p[5] = (bf16_t)exp2f(fmaf((float)hv[5], LOG2E, -cb.y));
        p[6] = (bf16_t)exp2f(fmaf((float)hv[6], LOG2E, -cb.z));
        p[7] = (bf16_t)exp2f(fmaf((float)hv[7], LOG2E, -cb.w));
        *(bf16x8*)(As + arow * APAD + aseg * 8) = p;
        __syncthreads();

        bf16x8 af[2], bg[4][2];
#pragma unroll
        for (int j = 0; j < 2; ++j)
            af[j] = *(const bf16x8*)(As + (wm2 + fr) * APAD + j * 32 + kb);
#pragma unroll
        for (int g = 0; g < 4; ++g)
#pragma unroll
            for (int j = 0; j < 2; ++j) {
                const int chunk = (j * 4 + u16) ^ fsw;
                bg[g][j] = *(const bf16x8*)(Bs + (wu + g * 16 + fr) * 64 + chunk * 8);
            }
#pragma unroll
        for (int j = 0; j < 2; ++j)
#pragma unroll
            for (int g = 0; g < 4; ++g)
                acc[g] = __builtin_amdgcn_mfma_f32_16x16x32_bf16(af[j], bg[g][j], acc[g], 0, 0, 0);
        __syncthreads();
    }

    // D layout: col(u) = lane&15, row(m) = (lane>>4)*4 + reg
    const int rbase = u16 * 4;
#pragma unroll
    for (int g = 0; g < 4; ++g) {
        const int u = u0 + wu + g * 16 + fr;
        const float bvv = bm[u];
#pragma unroll
        for (int r2 = 0; r2 < 4; ++r2) {
            const int m = m0 + wm2 + rbase + r2;
            const float v = acc[g][r2] + bvv;
            O[(long)m * 256 + u] = v > 0.0f ? v : 0.0f;
        }
    }
}

// ---------------------------------------------------------------------------
// FUSED first stage: blocks [0,2048) = x fp32->bf16 cvt; [2048,2240) = weight
// transpose prep. Independent work; block-uniform branch.
// ---------------------------------------------------------------------------
__global__ __launch_bounds__(256)
void cvt_prep(const float* __restrict__ x, bf16_t* __restrict__ x_bf,
              const float* __restrict__ Wq, const float* __restrict__ Wk,
              const float* __restrict__ Wm, const float* __restrict__ bq,
              const float* __restrict__ bk, bf16_t* __restrict__ WqkT,
              bf16_t* __restrict__ WmT, float* __restrict__ bqk)
{
    __shared__ float t[32][33];
    const int bid = blockIdx.x;
    if (bid < 2048) {
        const long i = ((long)bid * 256 + threadIdx.x) * 8;
        const float4 a = *(const float4*)(x + i);
        const float4 b = *(const float4*)(x + i + 4);
        bf16x8 o;
        o[0] = (bf16_t)a.x; o[1] = (bf16_t)a.y; o[2] = (bf16_t)a.z; o[3] = (bf16_t)a.w;
        o[4] = (bf16_t)b.x; o[5] = (bf16_t)b.y; o[6] = (bf16_t)b.z; o[7] = (bf16_t)b.w;
        *(bf16x8*)(x_bf + i) = o;
    } else {
        const int q = bid - 2048;        // 0..191
        const int z = q >> 6;            // 0..2
        const int xy = q & 63;
        const int n0 = (xy & 7) * 32, k0 = (xy >> 3) * 32;
        const float* W = (z == 0) ? Wq : (z == 1) ? Wk : Wm;
        bf16_t* Wt = (z == 0) ? WqkT : (z == 1) ? (WqkT + 256 * 256) : WmT;
        const int tx = threadIdx.x & 31, ty = threadIdx.x >> 5;
        for (int i2 = ty; i2 < 32; i2 += 8) t[i2][tx] = W[(k0 + i2) * 256 + n0 + tx];
        __syncthreads();
        for (int i2 = ty; i2 < 32; i2 += 8) Wt[(n0 + i2) * 256 + k0 + tx] = (bf16_t)t[tx][i2];
        if (q == 0) {
            bqk[threadIdx.x]       = bq[threadIdx.x];
            bqk[256 + threadIdx.x] = bk[threadIdx.x];
        }
    }
}

extern "C" void kernel_launch(void* const* d_in, const int* in_sizes, int n_in,
                              void* d_out, int out_size, void* d_ws, size_t ws_size,
                              hipStream_t stream)
{
    (void)in_sizes; (void)n_in; (void)out_size; (void)ws_size;
    const float* x  = (const float*)d_in[0];
    const float* Wq = (const float*)d_in[1];
    const float* bq = (const float*)d_in[2];
    const float* Wk = (const float*)d_in[3];
    const float* bk = (const float*)d_in[4];
    const float* Wm = (const float*)d_in[5];
    const float* bm = (const float*)d_in[6];
    float* out = (float*)d_out;

    // Workspace: St fp16 67.1 MB | x_bf 8.4 | qk 16.8 | qmT 8.4 |
    // WqkT 0.26 | WmT 0.13 | bqk | pm/pl 2x1 MB | c2 64 KB  (~103 MB)
    char* w = (char*)d_ws;
    _Float16* St   = (_Float16*)w;                  w += (size_t)BB * NN * NN * 2;
    bf16_t* x_bf   = (bf16_t*)w;                    w += (size_t)MTOT * 256 * 2;
    bf16_t* qk     = (bf16_t*)w;                    w += (size_t)MTOT * 512 * 2;
    bf16_t* qmT    = (bf16_t*)w;                    w += (size_t)MTOT * 256 * 2;
    bf16_t* WqkT   = (bf16_t*)w;                    w += 512 * 256 * 2;
    bf16_t* WmT    = (bf16_t*)w;                    w += 256 * 256 * 2;
    float*  bqk    = (float*)w;                     w += 512 * 4;
    float*  pm     = (float*)w;                     w += (size_t)BB * 16 * NN * 4;
    float*  pl     = (float*)w;                     w += (size_t)BB * 16 * NN * 4;
    float*  c2b    = (float*)w;

    // stage 1: cvt + weight prep (fused, 2240 blocks)
    cvt_prep<<<dim3(2240, 1, 1), 256, 0, stream>>>(
        x, x_bf, Wq, Wk, Wm, bq, bk, WqkT, WmT, bqk);

    // [q | k] = relu(x @ [Wq|Wk] + [bq|bk])  (bf16, ldc=512)
    // Grid (128,4): wgid = m + 128*n -> xcd = m%8, x panels L2-local (R16: -7us).
    gemm_nt<1, true><<<dim3(128, 4, 1), 256, 0, stream>>>(
        x_bf, WqkT, qk, bqk, 256, 256, 512, 0, 0, 0);

    // stage 3 (fused): St (fp16 + stats, blocks 0..2047, batch->XCD affinity)
    //                  ∥ qmT (bf16, blocks 2048..2303)
    gemm_fused<<<dim3(2304, 1, 1), 256, 0, stream>>>(
        qk, WmT, St, qmT, pm, pl);

    stats_combine<<<dim3(MTOT / 256), 256, 0, stream>>>(pm, pl, c2b);

    // out = relu(P~ @ qm + bm)  (v8 frozen, c2 from global)
    att_out<<<dim3(1024, 1, 1), 256, 0, stream>>>(St, qmT, c2b, bm, out);
}